// Round 12
// baseline (119.700 us; speedup 1.0000x reference)
//
#include <hip/hip_runtime.h>
#include <stdint.h>

// Problem constants (fixed by reference: R=C=256, S=32, B=64)
#define N_NEUR  65536
#define NNZ_E   2162688          // N * 33
#define NBUK    4096             // buckets of 16 destination rows
#define BSH     4                // bucket = row >> 4
#define BROWS   16
#define EPB     4096             // edges per bin block (528 blocks exactly)
#define NBLK_E  (NNZ_E / EPB)    // 528
#define CHUNK   2048             // gather staging chunk
#define EBUFSZ  (CHUNK + BROWS * 8)   // 2176: room for per-row pad-to-8

// Workspace layout (bytes):
//   xt      @ 0        : N*64*4 = 16,777,216   x transposed [N][64]
//   bcnt    @ 16777216 : 4096*4
//   boffs   @ 16793600 : 4096*4
//   gcur    @ 16809984 : 4096*4
//   tickets @ 16826368 : 256
//   csr     @ 16826624 : NNZ*8  = 17,301,504   packed (val:f32 | row:u16 | col:u16)

// ---------------- K1: fused transpose (blocks 0..1023) + bucket hist (rest) ----
__global__ __launch_bounds__(256) void k_front(const float* __restrict__ x,
                                               float* __restrict__ xt,
                                               const int* __restrict__ rows,
                                               int* __restrict__ bcnt) {
  __shared__ float smem[64 * 65];            // union: transpose tile / hist counters
  const int t = threadIdx.x;
  if (blockIdx.x < 1024) {
    float (*tile)[65] = (float (*)[65])smem;
    const int n0 = blockIdx.x * 64;
    const int lane = t & 63;
    const int w = t >> 6;
    #pragma unroll
    for (int bb = w; bb < 64; bb += 4)
      tile[bb][lane] = x[(size_t)bb * N_NEUR + n0 + lane];
    __syncthreads();
    #pragma unroll
    for (int nn = w; nn < 64; nn += 4)
      xt[(size_t)(n0 + nn) * 64 + lane] = tile[lane][nn];
  } else {
    int* lh = (int*)smem;                    // 4096 counters
    #pragma unroll
    for (int q = 0; q < NBUK / 256; ++q) lh[q * 256 + t] = 0;
    __syncthreads();
    const int e0 = (blockIdx.x - 1024) * EPB;
    #pragma unroll
    for (int k = 0; k < EPB / 256; ++k)
      atomicAdd(&lh[rows[e0 + k * 256 + t] >> BSH], 1);
    __syncthreads();
    #pragma unroll
    for (int q = 0; q < NBUK / 256; ++q) {
      const int v = lh[q * 256 + t];
      if (v) atomicAdd(&bcnt[q * 256 + t], v);
    }
  }
}

// ---------------- K2: exclusive scan over 4096 bucket counts (1 block) ----------------
__device__ inline int wave_incl_scan(int v, int lane) {
  #pragma unroll
  for (int off = 1; off < 64; off <<= 1) {
    int tv = __shfl_up(v, off, 64);
    if (lane >= off) v += tv;
  }
  return v;
}

__global__ __launch_bounds__(256) void k_bscan(const int* __restrict__ bcnt,
                                               int* __restrict__ boffs,
                                               int* __restrict__ gcur) {
  const int t = threadIdx.x, lane = t & 63, w = t >> 6;
  int c[16], s = 0;
  #pragma unroll
  for (int k = 0; k < 16; ++k) { c[k] = bcnt[t * 16 + k]; s += c[k]; }
  int incl = wave_incl_scan(s, lane);
  __shared__ int wsum[4];
  if (lane == 63) wsum[w] = incl;
  __syncthreads();
  int base = 0;
  for (int i = 0; i < w; ++i) base += wsum[i];
  int run = base + incl - s;
  #pragma unroll
  for (int k = 0; k < 16; ++k) {
    boffs[t * 16 + k] = run;
    gcur[t * 16 + k]  = run;
    run += c[k];
  }
}

// ---------------- K3: bucket-bin edges with coalesced chunk writes ----------------
// lc doubles as sbase after the reservation phase
__global__ __launch_bounds__(256) void k_bin(const int* __restrict__ rows,
                                             const float* __restrict__ vals,
                                             int* __restrict__ gcur,
                                             uint64_t* __restrict__ csr) {
  __shared__ int lc[NBUK];        // 16 KB  (count, then sbase)
  __shared__ int lofs[NBUK];      // 16 KB  (scan, then cursor)
  __shared__ int wsum[4];
  __shared__ uint64_t ebuf[EPB];  // 32 KB
  const int t = threadIdx.x, lane = t & 63, w = t >> 6;
  #pragma unroll
  for (int q = 0; q < NBUK / 256; ++q) lc[q * 256 + t] = 0;
  __syncthreads();
  const int e0 = blockIdx.x * EPB;
  int rcache[EPB / 256];
  #pragma unroll
  for (int k = 0; k < EPB / 256; ++k) {
    const int r = rows[e0 + k * 256 + t];
    rcache[k] = r;
    atomicAdd(&lc[r >> BSH], 1);
  }
  __syncthreads();
  {  // exclusive scan lc[4096] -> lofs (thread-chunked 16)
    int c[16], s = 0;
    #pragma unroll
    for (int k = 0; k < 16; ++k) { c[k] = lc[t * 16 + k]; s += c[k]; }
    int incl = wave_incl_scan(s, lane);
    if (lane == 63) wsum[w] = incl;
    __syncthreads();
    int base = 0;
    for (int i = 0; i < w; ++i) base += wsum[i];
    int run = base + incl - s;
    #pragma unroll
    for (int k = 0; k < 16; ++k) { lofs[t * 16 + k] = run; run += c[k]; }
  }
  __syncthreads();
  // reserve contiguous global chunk per non-empty bucket; lc[bb] := sbase
  #pragma unroll
  for (int q = 0; q < NBUK / 256; ++q) {
    const int bb = q * 256 + t;
    const int c = lc[bb];
    if (c) lc[bb] = atomicAdd(&gcur[bb], c) - lofs[bb];
  }
  __syncthreads();
  // local bucket-sort into ebuf (lofs doubles as cursor)
  #pragma unroll
  for (int k = 0; k < EPB / 256; ++k) {
    const int e = e0 + k * 256 + t;
    const int r = rcache[k];
    const uint32_t c = (uint32_t)e / 33u;      // cols[e] == e / 33 structurally
    const uint64_t pk = ((uint64_t)__float_as_uint(vals[e]) << 32) |
                        ((uint32_t)r << 16) | c;
    const int pos = atomicAdd(&lofs[r >> BSH], 1);
    ebuf[pos] = pk;
  }
  __syncthreads();
  // coalesced write-out: same-bucket runs -> consecutive global targets
  #pragma unroll
  for (int k = 0; k < EPB / 256; ++k) {
    const int idx = k * 256 + t;
    const uint64_t pk = ebuf[idx];
    const int bb = (int)((pk >> (16 + BSH)) & (NBUK - 1));
    csr[lc[bb] + idx] = pk;
  }
}

// ---------------- K4: ticketed per-bucket chunked sort (pad-to-8) + gather --------
// Global ticket in folded order: heavy sheet-border buckets (both ends) first,
// light interior last -> work-conserving schedule, no per-XCD tail.
__global__ __launch_bounds__(256) void k_gather(const float* __restrict__ xt,
                                                const int* __restrict__ boffs,
                                                const int* __restrict__ bcnt,
                                                const uint64_t* __restrict__ csr,
                                                int* __restrict__ tickets,
                                                float* __restrict__ out) {
  __shared__ uint64_t ebuf[EBUFSZ];    // 17.4 KB
  __shared__ float tile[BROWS][65];    // 4.2 KB
  __shared__ int lhist[BROWS], lofs[BROWS], lcur[BROWS], lpc[BROWS];
  __shared__ int g_s;
  const int t = threadIdx.x, lane = t & 63, w = t >> 6;
  if (t == 0) {
    const int k = atomicAdd(tickets, 1);
    g_s = (k & 1) ? (NBUK - 1 - (k >> 1)) : (k >> 1);   // folded: borders first
  }
  __syncthreads();
  const int g = g_s;
  const int r0 = g * BROWS;
  const int beg = boffs[g];
  const int cnt = bcnt[g];

  float acc[4] = {0.f, 0.f, 0.f, 0.f};   // wave w owns rows w*4 .. w*4+3

  for (int c0 = 0; c0 < cnt; c0 += CHUNK) {
    const int len = (cnt - c0 < CHUNK) ? (cnt - c0) : CHUNK;
    if (t < BROWS) lhist[t] = 0;
    __syncthreads();
    // stage to regs + LDS row histogram (single coalesced csr read)
    uint64_t E[CHUNK / 256];
    #pragma unroll
    for (int u = 0; u < CHUNK / 256; ++u) {
      const int i = u * 256 + t;
      if (i < len) {
        const uint64_t e = csr[beg + c0 + i];
        E[u] = e;
        atomicAdd(&lhist[(int)((e >> 16) & (BROWS - 1))], 1);
      }
    }
    __syncthreads();
    if (t == 0) {
      int run = 0;
      #pragma unroll
      for (int r = 0; r < BROWS; ++r) {
        const int c = lhist[r];
        const int pc = (c + 7) & ~7;          // pad each row to multiple of 8
        lofs[r] = run; lcur[r] = run; lpc[r] = pc;
        run += pc;                            // run <= len + 128 <= EBUFSZ
      }
    }
    __syncthreads();
    // zero-fill pad slots (<=7 per row): t<128 covers 16 rows x 8 pad idx
    if (t < 128) {
      const int r = t >> 3, pi = t & 7;
      const int c = lhist[r];
      if (pi < lpc[r] - c) ebuf[lofs[r] + c + pi] = 0ULL;   // col 0, val 0: no-op
    }
    // scatter into row-sorted LDS order
    #pragma unroll
    for (int u = 0; u < CHUNK / 256; ++u) {
      const int i = u * 256 + t;
      if (i < len) {
        const int rlo = (int)((E[u] >> 16) & (BROWS - 1));
        const int pos = atomicAdd(&lcur[rlo], 1);
        ebuf[pos] = E[u];
      }
    }
    __syncthreads();
    // gather: wave w owns rows w*4..w*4+3; remainder-free 8-deep MLP
    #pragma unroll
    for (int q = 0; q < 4; ++q) {
      const int rlo = w * 4 + q;
      const int s = __builtin_amdgcn_readfirstlane(lofs[rlo]);
      const int c = __builtin_amdgcn_readfirstlane(lpc[rlo]);   // multiple of 8
      float a0 = 0.f, a1 = 0.f, a2 = 0.f, a3 = 0.f;
      for (int k = 0; k < c; k += 8) {
        const uint64_t e0 = ebuf[s+k+0], e1 = ebuf[s+k+1], e2 = ebuf[s+k+2], e3 = ebuf[s+k+3];
        const uint64_t e4 = ebuf[s+k+4], e5 = ebuf[s+k+5], e6 = ebuf[s+k+6], e7 = ebuf[s+k+7];
        const float p0 = xt[(int)(e0 & 0xFFFF) * 64 + lane];
        const float p1 = xt[(int)(e1 & 0xFFFF) * 64 + lane];
        const float p2 = xt[(int)(e2 & 0xFFFF) * 64 + lane];
        const float p3 = xt[(int)(e3 & 0xFFFF) * 64 + lane];
        const float p4 = xt[(int)(e4 & 0xFFFF) * 64 + lane];
        const float p5 = xt[(int)(e5 & 0xFFFF) * 64 + lane];
        const float p6 = xt[(int)(e6 & 0xFFFF) * 64 + lane];
        const float p7 = xt[(int)(e7 & 0xFFFF) * 64 + lane];
        a0 = fmaf(__uint_as_float((uint32_t)(e0 >> 32)), p0, a0);
        a1 = fmaf(__uint_as_float((uint32_t)(e1 >> 32)), p1, a1);
        a2 = fmaf(__uint_as_float((uint32_t)(e2 >> 32)), p2, a2);
        a3 = fmaf(__uint_as_float((uint32_t)(e3 >> 32)), p3, a3);
        a0 = fmaf(__uint_as_float((uint32_t)(e4 >> 32)), p4, a0);
        a1 = fmaf(__uint_as_float((uint32_t)(e5 >> 32)), p5, a1);
        a2 = fmaf(__uint_as_float((uint32_t)(e6 >> 32)), p6, a2);
        a3 = fmaf(__uint_as_float((uint32_t)(e7 >> 32)), p7, a3);
      }
      acc[q] += (a0 + a1) + (a2 + a3);
    }
    __syncthreads();   // ebuf/lhist reused next chunk
  }

  // each row owned by exactly one wave: direct tile write, no atomics
  #pragma unroll
  for (int q = 0; q < 4; ++q)
    tile[w * 4 + q][lane] = acc[q];
  __syncthreads();
  // coalesced write-out: out[b][r0+rl]
  #pragma unroll
  for (int p = 0; p < (BROWS * 64) / 256; ++p) {
    const int idx = p * 256 + t;
    const int bb = idx >> 4;
    const int rl = idx & (BROWS - 1);
    out[(size_t)bb * N_NEUR + r0 + rl] = tile[rl][bb];
  }
}

extern "C" void kernel_launch(void* const* d_in, const int* in_sizes, int n_in,
                              void* d_out, int out_size, void* d_ws, size_t ws_size,
                              hipStream_t stream) {
  const float* x    = (const float*)d_in[0];
  const float* vals = (const float*)d_in[1];
  const int*   rows = (const int*)d_in[2];
  float* out = (float*)d_out;

  char* ws = (char*)d_ws;
  float*    xt      = (float*)   (ws + 0);
  int*      bcnt    = (int*)     (ws + 16777216);
  int*      boffs   = (int*)     (ws + 16793600);
  int*      gcur    = (int*)     (ws + 16809984);
  int*      tickets = (int*)     (ws + 16826368);
  uint64_t* csr     = (uint64_t*)(ws + 16826624);

  hipMemsetAsync(bcnt, 0, 49408, stream);   // bcnt + boffs + gcur + tickets
  k_front<<<1024 + NBLK_E, 256, 0, stream>>>(x, xt, rows, bcnt);
  k_bscan<<<1, 256, 0, stream>>>(bcnt, boffs, gcur);
  k_bin<<<NBLK_E, 256, 0, stream>>>(rows, vals, gcur, csr);
  k_gather<<<NBUK, 256, 0, stream>>>(xt, boffs, bcnt, csr, tickets, out);
}

// Round 13
// 114.862 us; speedup vs baseline: 1.0421x; 1.0421x over previous
//
#include <hip/hip_runtime.h>
#include <stdint.h>

// Problem constants (fixed by reference: R=C=256, S=32, B=64)
#define N_NEUR  65536
#define NNZ_E   2162688          // N * 33
#define NBUK    4096             // buckets of 16 destination rows
#define BSH     4                // bucket = row >> 4
#define BROWS   16
#define EPB     4096             // edges per bin block (528 blocks exactly)
#define NBLK_E  (NNZ_E / EPB)    // 528
#define CHUNK   2048             // gather staging chunk
#define EBUFSZ  (CHUNK + BROWS * 8)   // 2176: room for per-row pad-to-8

// Workspace layout (bytes):
//   xt    @ 0         : N*64*4 = 16,777,216   x transposed [N][64]
//   bcnt  @ 16777216  : 4096*4
//   boffs @ 16793600  : 4096*4
//   gcur  @ 16809984  : 4096*4
//   csr   @ 16826368  : NNZ*8  = 17,301,504   packed (val:f32 | row:u16 | col:u16)

// ---------------- K1: fused transpose (blocks 0..1023) + bucket hist (rest) ----
__global__ __launch_bounds__(256) void k_front(const float* __restrict__ x,
                                               float* __restrict__ xt,
                                               const int* __restrict__ rows,
                                               int* __restrict__ bcnt) {
  __shared__ float smem[64 * 65];            // union: transpose tile / hist counters
  const int t = threadIdx.x;
  if (blockIdx.x < 1024) {
    float (*tile)[65] = (float (*)[65])smem;
    const int n0 = blockIdx.x * 64;
    const int lane = t & 63;
    const int w = t >> 6;
    #pragma unroll
    for (int bb = w; bb < 64; bb += 4)
      tile[bb][lane] = x[(size_t)bb * N_NEUR + n0 + lane];
    __syncthreads();
    #pragma unroll
    for (int nn = w; nn < 64; nn += 4)
      xt[(size_t)(n0 + nn) * 64 + lane] = tile[lane][nn];
  } else {
    int* lh = (int*)smem;                    // 4096 counters
    #pragma unroll
    for (int q = 0; q < NBUK / 256; ++q) lh[q * 256 + t] = 0;
    __syncthreads();
    const int e0 = (blockIdx.x - 1024) * EPB;
    #pragma unroll
    for (int k = 0; k < EPB / 256; ++k)
      atomicAdd(&lh[rows[e0 + k * 256 + t] >> BSH], 1);
    __syncthreads();
    #pragma unroll
    for (int q = 0; q < NBUK / 256; ++q) {
      const int v = lh[q * 256 + t];
      if (v) atomicAdd(&bcnt[q * 256 + t], v);
    }
  }
}

// ---------------- K2: exclusive scan over 4096 bucket counts (1 block) ----------------
__device__ inline int wave_incl_scan(int v, int lane) {
  #pragma unroll
  for (int off = 1; off < 64; off <<= 1) {
    int tv = __shfl_up(v, off, 64);
    if (lane >= off) v += tv;
  }
  return v;
}

__global__ __launch_bounds__(256) void k_bscan(const int* __restrict__ bcnt,
                                               int* __restrict__ boffs,
                                               int* __restrict__ gcur) {
  const int t = threadIdx.x, lane = t & 63, w = t >> 6;
  int c[16], s = 0;
  #pragma unroll
  for (int k = 0; k < 16; ++k) { c[k] = bcnt[t * 16 + k]; s += c[k]; }
  int incl = wave_incl_scan(s, lane);
  __shared__ int wsum[4];
  if (lane == 63) wsum[w] = incl;
  __syncthreads();
  int base = 0;
  for (int i = 0; i < w; ++i) base += wsum[i];
  int run = base + incl - s;
  #pragma unroll
  for (int k = 0; k < 16; ++k) {
    boffs[t * 16 + k] = run;
    gcur[t * 16 + k]  = run;
    run += c[k];
  }
}

// ---------------- K3: bucket-bin edges with coalesced chunk writes ----------------
// lc doubles as sbase after the reservation phase
__global__ __launch_bounds__(256) void k_bin(const int* __restrict__ rows,
                                             const float* __restrict__ vals,
                                             int* __restrict__ gcur,
                                             uint64_t* __restrict__ csr) {
  __shared__ int lc[NBUK];        // 16 KB  (count, then sbase)
  __shared__ int lofs[NBUK];      // 16 KB  (scan, then cursor)
  __shared__ int wsum[4];
  __shared__ uint64_t ebuf[EPB];  // 32 KB
  const int t = threadIdx.x, lane = t & 63, w = t >> 6;
  #pragma unroll
  for (int q = 0; q < NBUK / 256; ++q) lc[q * 256 + t] = 0;
  __syncthreads();
  const int e0 = blockIdx.x * EPB;
  int rcache[EPB / 256];
  #pragma unroll
  for (int k = 0; k < EPB / 256; ++k) {
    const int r = rows[e0 + k * 256 + t];
    rcache[k] = r;
    atomicAdd(&lc[r >> BSH], 1);
  }
  __syncthreads();
  {  // exclusive scan lc[4096] -> lofs (thread-chunked 16)
    int c[16], s = 0;
    #pragma unroll
    for (int k = 0; k < 16; ++k) { c[k] = lc[t * 16 + k]; s += c[k]; }
    int incl = wave_incl_scan(s, lane);
    if (lane == 63) wsum[w] = incl;
    __syncthreads();
    int base = 0;
    for (int i = 0; i < w; ++i) base += wsum[i];
    int run = base + incl - s;
    #pragma unroll
    for (int k = 0; k < 16; ++k) { lofs[t * 16 + k] = run; run += c[k]; }
  }
  __syncthreads();
  // reserve contiguous global chunk per non-empty bucket; lc[bb] := sbase
  #pragma unroll
  for (int q = 0; q < NBUK / 256; ++q) {
    const int bb = q * 256 + t;
    const int c = lc[bb];
    if (c) lc[bb] = atomicAdd(&gcur[bb], c) - lofs[bb];
  }
  __syncthreads();
  // local bucket-sort into ebuf (lofs doubles as cursor)
  #pragma unroll
  for (int k = 0; k < EPB / 256; ++k) {
    const int e = e0 + k * 256 + t;
    const int r = rcache[k];
    const uint32_t c = (uint32_t)e / 33u;      // cols[e] == e / 33 structurally
    const uint64_t pk = ((uint64_t)__float_as_uint(vals[e]) << 32) |
                        ((uint32_t)r << 16) | c;
    const int pos = atomicAdd(&lofs[r >> BSH], 1);
    ebuf[pos] = pk;
  }
  __syncthreads();
  // coalesced write-out: same-bucket runs -> consecutive global targets
  #pragma unroll
  for (int k = 0; k < EPB / 256; ++k) {
    const int idx = k * 256 + t;
    const uint64_t pk = ebuf[idx];
    const int bb = (int)((pk >> (16 + BSH)) & (NBUK - 1));
    csr[lc[bb] + idx] = pk;
  }
}

// ---------------- K4: per-bucket chunked sort + EVEN wave-split gather ----------
// Grid 8192: blocks 0..4095 = sub 0 (static XCD swizzle, as R11); 4096..8191 =
// sub 1, active only for buckets with cnt > CHUNK (alternating chunks).
// Within a chunk: row-sorted pad-to-8 stream split EVENLY across the 4 waves by
// 8-entry windows; row id from window's first entry (always real); on uniform
// row change, flush accs into tile via LDS float atomicAdd. Removes the
// heavy-row serial tail that pinned occupancy at ~27%.
__global__ __launch_bounds__(256) void k_gather(const float* __restrict__ xt,
                                                const int* __restrict__ boffs,
                                                const int* __restrict__ bcnt,
                                                const uint64_t* __restrict__ csr,
                                                float* __restrict__ out) {
  __shared__ uint64_t ebuf[EBUFSZ];    // 17.4 KB
  __shared__ float tile[BROWS][65];    // 4.2 KB
  __shared__ int lhist[BROWS], lofs[BROWS], lcur[BROWS], lpc[BROWS];
  __shared__ int ptot_s;
  const int t = threadIdx.x, lane = t & 63, w = t >> 6;
  const int sub = blockIdx.x >> 12;                    // 0 or 1
  const int b = blockIdx.x & (NBUK - 1);
  const int g = (b & 7) * (NBUK / 8) + (b >> 3);       // XCD-chunked swizzle
  const int r0 = g * BROWS;
  const int beg = boffs[g];
  const int cnt = bcnt[g];
  if (sub && cnt <= CHUNK) return;                     // uniform early exit
  const bool multi = cnt > CHUNK;

  for (int i = t; i < BROWS * 65; i += 256) ((float*)tile)[i] = 0.f;

  for (int c0 = sub * CHUNK; c0 < cnt; c0 += 2 * CHUNK) {
    const int len = (cnt - c0 < CHUNK) ? (cnt - c0) : CHUNK;
    if (t < BROWS) lhist[t] = 0;
    __syncthreads();   // covers tile zero (iter 0) and prev-iter gather reads
    // stage to regs + LDS row histogram (single coalesced csr read)
    uint64_t E[CHUNK / 256];
    #pragma unroll
    for (int u = 0; u < CHUNK / 256; ++u) {
      const int i = u * 256 + t;
      if (i < len) {
        const uint64_t e = csr[beg + c0 + i];
        E[u] = e;
        atomicAdd(&lhist[(int)((e >> 16) & (BROWS - 1))], 1);
      }
    }
    __syncthreads();
    if (t == 0) {
      int run = 0;
      #pragma unroll
      for (int r = 0; r < BROWS; ++r) {
        const int c = lhist[r];
        const int pc = (c + 7) & ~7;          // pad each row to multiple of 8
        lofs[r] = run; lcur[r] = run; lpc[r] = pc;
        run += pc;                            // run <= len + 128 <= EBUFSZ
      }
      ptot_s = run;
    }
    __syncthreads();
    // zero-fill pad slots (<=7 per row)
    if (t < 128) {
      const int r = t >> 3, pi = t & 7;
      const int c = lhist[r];
      if (pi < lpc[r] - c) ebuf[lofs[r] + c + pi] = 0ULL;   // col 0, val 0: no-op
    }
    // scatter into row-sorted LDS order
    #pragma unroll
    for (int u = 0; u < CHUNK / 256; ++u) {
      const int i = u * 256 + t;
      if (i < len) {
        const int rlo = (int)((E[u] >> 16) & (BROWS - 1));
        const int pos = atomicAdd(&lcur[rlo], 1);
        ebuf[pos] = E[u];
      }
    }
    __syncthreads();
    // EVEN split: wave w takes windows [nw*w/4, nw*(w+1)/4)
    const int nw = __builtin_amdgcn_readfirstlane(ptot_s) >> 3;
    const int wi0 = (nw * w) >> 2;
    const int wi1 = (nw * (w + 1)) >> 2;
    float a0 = 0.f, a1 = 0.f, a2 = 0.f, a3 = 0.f;
    int cur = -1;
    for (int wi = wi0; wi < wi1; ++wi) {
      const int s = wi << 3;
      const uint64_t e0 = ebuf[s+0], e1 = ebuf[s+1], e2 = ebuf[s+2], e3 = ebuf[s+3];
      const uint64_t e4 = ebuf[s+4], e5 = ebuf[s+5], e6 = ebuf[s+6], e7 = ebuf[s+7];
      const int row = (int)((e0 >> 16) & (BROWS - 1));   // e0 is always real
      if (row != cur) {                                   // uniform, rare
        if (cur >= 0) atomicAdd(&tile[cur][lane], (a0 + a1) + (a2 + a3));
        cur = row; a0 = a1 = a2 = a3 = 0.f;
      }
      const float p0 = xt[(int)(e0 & 0xFFFF) * 64 + lane];
      const float p1 = xt[(int)(e1 & 0xFFFF) * 64 + lane];
      const float p2 = xt[(int)(e2 & 0xFFFF) * 64 + lane];
      const float p3 = xt[(int)(e3 & 0xFFFF) * 64 + lane];
      const float p4 = xt[(int)(e4 & 0xFFFF) * 64 + lane];
      const float p5 = xt[(int)(e5 & 0xFFFF) * 64 + lane];
      const float p6 = xt[(int)(e6 & 0xFFFF) * 64 + lane];
      const float p7 = xt[(int)(e7 & 0xFFFF) * 64 + lane];
      a0 = fmaf(__uint_as_float((uint32_t)(e0 >> 32)), p0, a0);
      a1 = fmaf(__uint_as_float((uint32_t)(e1 >> 32)), p1, a1);
      a2 = fmaf(__uint_as_float((uint32_t)(e2 >> 32)), p2, a2);
      a3 = fmaf(__uint_as_float((uint32_t)(e3 >> 32)), p3, a3);
      a0 = fmaf(__uint_as_float((uint32_t)(e4 >> 32)), p4, a0);
      a1 = fmaf(__uint_as_float((uint32_t)(e5 >> 32)), p5, a1);
      a2 = fmaf(__uint_as_float((uint32_t)(e6 >> 32)), p6, a2);
      a3 = fmaf(__uint_as_float((uint32_t)(e7 >> 32)), p7, a3);
    }
    if (cur >= 0) atomicAdd(&tile[cur][lane], (a0 + a1) + (a2 + a3));
  }
  __syncthreads();   // all flushes done

  // write-out: single-chunk buckets (sub 0 exclusive owner) plain-store;
  // multi-chunk buckets merge via global atomicAdd on pre-zeroed out.
  #pragma unroll
  for (int p = 0; p < (BROWS * 64) / 256; ++p) {
    const int idx = p * 256 + t;
    const int bb = idx >> 4;
    const int rl = idx & (BROWS - 1);
    if (multi) atomicAdd(&out[(size_t)bb * N_NEUR + r0 + rl], tile[rl][bb]);
    else       out[(size_t)bb * N_NEUR + r0 + rl] = tile[rl][bb];
  }
}

extern "C" void kernel_launch(void* const* d_in, const int* in_sizes, int n_in,
                              void* d_out, int out_size, void* d_ws, size_t ws_size,
                              hipStream_t stream) {
  const float* x    = (const float*)d_in[0];
  const float* vals = (const float*)d_in[1];
  const int*   rows = (const int*)d_in[2];
  float* out = (float*)d_out;

  char* ws = (char*)d_ws;
  float*    xt    = (float*)   (ws + 0);
  int*      bcnt  = (int*)     (ws + 16777216);
  int*      boffs = (int*)     (ws + 16793600);
  int*      gcur  = (int*)     (ws + 16809984);
  uint64_t* csr   = (uint64_t*)(ws + 16826368);

  hipMemsetAsync(bcnt, 0, 3 * NBUK * sizeof(int), stream);
  hipMemsetAsync(out, 0, (size_t)64 * N_NEUR * sizeof(float), stream);  // for atomic merge
  k_front<<<1024 + NBLK_E, 256, 0, stream>>>(x, xt, rows, bcnt);
  k_bscan<<<1, 256, 0, stream>>>(bcnt, boffs, gcur);
  k_bin<<<NBLK_E, 256, 0, stream>>>(rows, vals, gcur, csr);
  k_gather<<<2 * NBUK, 256, 0, stream>>>(xt, boffs, bcnt, csr, out);
}

// Round 14
// 90.008 us; speedup vs baseline: 1.3299x; 1.2761x over previous
//
#include <hip/hip_runtime.h>
#include <stdint.h>

// Problem constants (fixed by reference: R=C=256, S=32, B=64)
#define N_NEUR  65536
#define NNZ_E   2162688          // N * 33
#define NBUK    4096             // buckets of 16 destination rows
#define BSH     4                // bucket = row >> 4
#define BROWS   16
#define EPB     4096             // edges per bin block (528 blocks exactly)
#define NBLK_E  (NNZ_E / EPB)    // 528
#define CHUNK   2048             // gather staging chunk
#define EBUFSZ  (CHUNK + BROWS * 16)  // 2304: room for per-row pad-to-16

// Workspace layout (bytes)  (xt region kept at 16MB for layout stability):
//   xt    @ 0         : N*64*2 = 8,388,608 used (bf16 [N][64])
//   bcnt  @ 16777216  : 4096*4
//   boffs @ 16793600  : 4096*4
//   gcur  @ 16809984  : 4096*4
//   csr   @ 16826368  : NNZ*8  = 17,301,504   packed (val:f32 | row:u16 | col:u16)

__device__ inline unsigned short f2bf(float f) {   // round-to-nearest-even
  const uint32_t u = __float_as_uint(f);
  return (unsigned short)((u + 0x7FFFu + ((u >> 16) & 1u)) >> 16);
}

// ---------------- K1: fused transpose->bf16 (blocks 0..1023) + bucket hist ------
__global__ __launch_bounds__(256) void k_front(const float* __restrict__ x,
                                               unsigned short* __restrict__ xtb,
                                               const int* __restrict__ rows,
                                               int* __restrict__ bcnt) {
  __shared__ float smem[64 * 65];            // union: transpose tile / hist counters
  const int t = threadIdx.x;
  if (blockIdx.x < 1024) {
    float (*tile)[65] = (float (*)[65])smem;
    const int n0 = blockIdx.x * 64;
    const int lane = t & 63;
    const int w = t >> 6;
    #pragma unroll
    for (int bb = w; bb < 64; bb += 4)
      tile[bb][lane] = x[(size_t)bb * N_NEUR + n0 + lane];
    __syncthreads();
    #pragma unroll
    for (int nn = w; nn < 64; nn += 4)
      xtb[(size_t)(n0 + nn) * 64 + lane] = f2bf(tile[lane][nn]);
  } else {
    int* lh = (int*)smem;                    // 4096 counters
    #pragma unroll
    for (int q = 0; q < NBUK / 256; ++q) lh[q * 256 + t] = 0;
    __syncthreads();
    const int e0 = (blockIdx.x - 1024) * EPB;
    #pragma unroll
    for (int k = 0; k < EPB / 256; ++k)
      atomicAdd(&lh[rows[e0 + k * 256 + t] >> BSH], 1);
    __syncthreads();
    #pragma unroll
    for (int q = 0; q < NBUK / 256; ++q) {
      const int v = lh[q * 256 + t];
      if (v) atomicAdd(&bcnt[q * 256 + t], v);
    }
  }
}

// ---------------- K2: exclusive scan over 4096 bucket counts (1 block) ----------------
__device__ inline int wave_incl_scan(int v, int lane) {
  #pragma unroll
  for (int off = 1; off < 64; off <<= 1) {
    int tv = __shfl_up(v, off, 64);
    if (lane >= off) v += tv;
  }
  return v;
}

__global__ __launch_bounds__(256) void k_bscan(const int* __restrict__ bcnt,
                                               int* __restrict__ boffs,
                                               int* __restrict__ gcur) {
  const int t = threadIdx.x, lane = t & 63, w = t >> 6;
  int c[16], s = 0;
  #pragma unroll
  for (int k = 0; k < 16; ++k) { c[k] = bcnt[t * 16 + k]; s += c[k]; }
  int incl = wave_incl_scan(s, lane);
  __shared__ int wsum[4];
  if (lane == 63) wsum[w] = incl;
  __syncthreads();
  int base = 0;
  for (int i = 0; i < w; ++i) base += wsum[i];
  int run = base + incl - s;
  #pragma unroll
  for (int k = 0; k < 16; ++k) {
    boffs[t * 16 + k] = run;
    gcur[t * 16 + k]  = run;
    run += c[k];
  }
}

// ---------------- K3: bucket-bin edges with coalesced chunk writes ----------------
// lc doubles as sbase after the reservation phase
__global__ __launch_bounds__(256) void k_bin(const int* __restrict__ rows,
                                             const float* __restrict__ vals,
                                             int* __restrict__ gcur,
                                             uint64_t* __restrict__ csr) {
  __shared__ int lc[NBUK];        // 16 KB  (count, then sbase)
  __shared__ int lofs[NBUK];      // 16 KB  (scan, then cursor)
  __shared__ int wsum[4];
  __shared__ uint64_t ebuf[EPB];  // 32 KB
  const int t = threadIdx.x, lane = t & 63, w = t >> 6;
  #pragma unroll
  for (int q = 0; q < NBUK / 256; ++q) lc[q * 256 + t] = 0;
  __syncthreads();
  const int e0 = blockIdx.x * EPB;
  int rcache[EPB / 256];
  #pragma unroll
  for (int k = 0; k < EPB / 256; ++k) {
    const int r = rows[e0 + k * 256 + t];
    rcache[k] = r;
    atomicAdd(&lc[r >> BSH], 1);
  }
  __syncthreads();
  {  // exclusive scan lc[4096] -> lofs (thread-chunked 16)
    int c[16], s = 0;
    #pragma unroll
    for (int k = 0; k < 16; ++k) { c[k] = lc[t * 16 + k]; s += c[k]; }
    int incl = wave_incl_scan(s, lane);
    if (lane == 63) wsum[w] = incl;
    __syncthreads();
    int base = 0;
    for (int i = 0; i < w; ++i) base += wsum[i];
    int run = base + incl - s;
    #pragma unroll
    for (int k = 0; k < 16; ++k) { lofs[t * 16 + k] = run; run += c[k]; }
  }
  __syncthreads();
  // reserve contiguous global chunk per non-empty bucket; lc[bb] := sbase
  #pragma unroll
  for (int q = 0; q < NBUK / 256; ++q) {
    const int bb = q * 256 + t;
    const int c = lc[bb];
    if (c) lc[bb] = atomicAdd(&gcur[bb], c) - lofs[bb];
  }
  __syncthreads();
  // local bucket-sort into ebuf (lofs doubles as cursor)
  #pragma unroll
  for (int k = 0; k < EPB / 256; ++k) {
    const int e = e0 + k * 256 + t;
    const int r = rcache[k];
    const uint32_t c = (uint32_t)e / 33u;      // cols[e] == e / 33 structurally
    const uint64_t pk = ((uint64_t)__float_as_uint(vals[e]) << 32) |
                        ((uint32_t)r << 16) | c;
    const int pos = atomicAdd(&lofs[r >> BSH], 1);
    ebuf[pos] = pk;
  }
  __syncthreads();
  // coalesced write-out: same-bucket runs -> consecutive global targets
  #pragma unroll
  for (int k = 0; k < EPB / 256; ++k) {
    const int idx = k * 256 + t;
    const uint64_t pk = ebuf[idx];
    const int bb = (int)((pk >> (16 + BSH)) & (NBUK - 1));
    csr[lc[bb] + idx] = pk;
  }
}

// ---------------- K4: per-bucket chunked sort (pad-to-16) + bf16 pair gather ------
// Half-wave h takes edge 2k+h of each pair; lane p in [0,32) loads one uint =
// bf16 batches (2p, 2p+1) of its half's edge. One 256B wave-instr covers 2 edges.
__global__ __launch_bounds__(256) void k_gather(const unsigned short* __restrict__ xtb,
                                                const int* __restrict__ boffs,
                                                const int* __restrict__ bcnt,
                                                const uint64_t* __restrict__ csr,
                                                float* __restrict__ out) {
  __shared__ uint64_t ebuf[EBUFSZ];    // 18.4 KB
  __shared__ float tile[BROWS][66];    // 4.2 KB (even stride for pair writes)
  __shared__ int lhist[BROWS], lofs[BROWS], lcur[BROWS], lpc[BROWS];
  const int t = threadIdx.x, lane = t & 63, w = t >> 6;
  const int h = lane >> 5, p = lane & 31;
  const int bid = blockIdx.x;
  const int g = (bid & 7) * (NBUK / 8) + (bid >> 3);   // XCD-chunked swizzle
  const int r0 = g * BROWS;
  const int beg = boffs[g];
  const int cnt = bcnt[g];
  const uint32_t* __restrict__ xtu = (const uint32_t*)xtb;  // [N][32] uints

  float accx[4] = {0.f, 0.f, 0.f, 0.f};   // wave w owns rows w*4 .. w*4+3
  float accy[4] = {0.f, 0.f, 0.f, 0.f};

  for (int c0 = 0; c0 < cnt; c0 += CHUNK) {
    const int len = (cnt - c0 < CHUNK) ? (cnt - c0) : CHUNK;
    if (t < BROWS) lhist[t] = 0;
    __syncthreads();
    // stage to regs + LDS row histogram (single coalesced csr read)
    uint64_t E[CHUNK / 256];
    #pragma unroll
    for (int u = 0; u < CHUNK / 256; ++u) {
      const int i = u * 256 + t;
      if (i < len) {
        const uint64_t e = csr[beg + c0 + i];
        E[u] = e;
        atomicAdd(&lhist[(int)((e >> 16) & (BROWS - 1))], 1);
      }
    }
    __syncthreads();
    if (t == 0) {
      int run = 0;
      #pragma unroll
      for (int r = 0; r < BROWS; ++r) {
        const int c = lhist[r];
        const int pc = (c + 15) & ~15;        // pad each row to multiple of 16
        lofs[r] = run; lcur[r] = run; lpc[r] = pc;
        run += pc;                            // run <= len + 240 <= EBUFSZ
      }
    }
    __syncthreads();
    // zero-fill pad slots (<=15 per row): 256 threads cover 16 rows x 16 idx
    {
      const int r = t >> 4, pi = t & 15;
      const int c = lhist[r];
      if (pi < lpc[r] - c) ebuf[lofs[r] + c + pi] = 0ULL;   // col 0, val 0: no-op
    }
    // scatter into row-sorted LDS order
    #pragma unroll
    for (int u = 0; u < CHUNK / 256; ++u) {
      const int i = u * 256 + t;
      if (i < len) {
        const int rlo = (int)((E[u] >> 16) & (BROWS - 1));
        const int pos = atomicAdd(&lcur[rlo], 1);
        ebuf[pos] = E[u];
      }
    }
    __syncthreads();
    // gather: wave w owns rows w*4..w*4+3; 8 pair-iters = 16 edges in flight
    #pragma unroll
    for (int q = 0; q < 4; ++q) {
      const int rlo = w * 4 + q;
      const int s = __builtin_amdgcn_readfirstlane(lofs[rlo]);
      const int npair = __builtin_amdgcn_readfirstlane(lpc[rlo]) >> 1; // mult of 8
      float ax = 0.f, ay = 0.f, bx = 0.f, by = 0.f;
      for (int ti = 0; ti < npair; ti += 8) {
        uint64_t e[8]; uint32_t xv[8];
        #pragma unroll
        for (int u = 0; u < 8; ++u) e[u] = ebuf[s + 2 * (ti + u) + h];
        #pragma unroll
        for (int u = 0; u < 8; ++u)
          xv[u] = xtu[(int)(e[u] & 0xFFFF) * 32 + p];     // 2 bf16 batches
        #pragma unroll
        for (int u = 0; u < 8; ++u) {
          const float v  = __uint_as_float((uint32_t)(e[u] >> 32));
          const float lo = __uint_as_float(xv[u] << 16);          // batch 2p
          const float hi = __uint_as_float(xv[u] & 0xFFFF0000u);  // batch 2p+1
          if (u & 1) { bx = fmaf(v, lo, bx); by = fmaf(v, hi, by); }
          else       { ax = fmaf(v, lo, ax); ay = fmaf(v, hi, ay); }
        }
      }
      accx[q] += ax + bx;
      accy[q] += ay + by;
    }
    __syncthreads();   // ebuf/lhist reused next chunk
  }

  // combine halves (edge-parity split) and write tile
  #pragma unroll
  for (int q = 0; q < 4; ++q) {
    float sx = accx[q] + __shfl_xor(accx[q], 32, 64);
    float sy = accy[q] + __shfl_xor(accy[q], 32, 64);
    if (h == 0) {
      tile[w * 4 + q][2 * p]     = sx;
      tile[w * 4 + q][2 * p + 1] = sy;
    }
  }
  __syncthreads();
  // coalesced write-out: out[b][r0+rl]
  #pragma unroll
  for (int pp = 0; pp < (BROWS * 64) / 256; ++pp) {
    const int idx = pp * 256 + t;
    const int bb = idx >> 4;
    const int rl = idx & (BROWS - 1);
    out[(size_t)bb * N_NEUR + r0 + rl] = tile[rl][bb];
  }
}

extern "C" void kernel_launch(void* const* d_in, const int* in_sizes, int n_in,
                              void* d_out, int out_size, void* d_ws, size_t ws_size,
                              hipStream_t stream) {
  const float* x    = (const float*)d_in[0];
  const float* vals = (const float*)d_in[1];
  const int*   rows = (const int*)d_in[2];
  float* out = (float*)d_out;

  char* ws = (char*)d_ws;
  unsigned short* xtb = (unsigned short*)(ws + 0);
  int*      bcnt  = (int*)     (ws + 16777216);
  int*      boffs = (int*)     (ws + 16793600);
  int*      gcur  = (int*)     (ws + 16809984);
  uint64_t* csr   = (uint64_t*)(ws + 16826368);

  hipMemsetAsync(bcnt, 0, NBUK * sizeof(int), stream);
  k_front<<<1024 + NBLK_E, 256, 0, stream>>>(x, xtb, rows, bcnt);
  k_bscan<<<1, 256, 0, stream>>>(bcnt, boffs, gcur);
  k_bin<<<NBLK_E, 256, 0, stream>>>(rows, vals, gcur, csr);
  k_gather<<<NBUK, 256, 0, stream>>>(xtb, boffs, bcnt, csr, out);
}

// Round 15
// 88.301 us; speedup vs baseline: 1.3556x; 1.0193x over previous
//
#include <hip/hip_runtime.h>
#include <stdint.h>

// Problem constants (fixed by reference: R=C=256, S=32, B=64)
#define N_NEUR  65536
#define NNZ_E   2162688          // N * 33
#define NBUK    4096             // buckets of 16 destination rows
#define BSH     4                // bucket = row >> 4
#define BROWS   16
#define EPB     4096             // edges per bin block (528 blocks exactly)
#define NBLK_E  (NNZ_E / EPB)    // 528
#define CHUNK   1536             // gather staging chunk (13.3 KB ebuf -> 8 blk/CU)
#define EBUFSZ  (CHUNK + BROWS * 8)   // 1664: room for per-row pad-to-8

// Workspace layout (bytes)  (xt region kept at 16MB for layout stability):
//   xt    @ 0         : N*64*2 = 8,388,608 used (bf16 [N][64])
//   bcnt  @ 16777216  : 4096*4
//   boffs @ 16793600  : 4096*4
//   gcur  @ 16809984  : 4096*4
//   csr   @ 16826368  : NNZ*8  = 17,301,504   packed (val:f32 | row:u16 | col:u16)

__device__ inline unsigned short f2bf(float f) {   // round-to-nearest-even
  const uint32_t u = __float_as_uint(f);
  return (unsigned short)((u + 0x7FFFu + ((u >> 16) & 1u)) >> 16);
}

// ---------------- K1: fused transpose->bf16 (blocks 0..1023) + bucket hist ------
__global__ __launch_bounds__(256) void k_front(const float* __restrict__ x,
                                               unsigned short* __restrict__ xtb,
                                               const int* __restrict__ rows,
                                               int* __restrict__ bcnt) {
  __shared__ float smem[64 * 65];            // union: transpose tile / hist counters
  const int t = threadIdx.x;
  if (blockIdx.x < 1024) {
    float (*tile)[65] = (float (*)[65])smem;
    const int n0 = blockIdx.x * 64;
    const int lane = t & 63;
    const int w = t >> 6;
    #pragma unroll
    for (int bb = w; bb < 64; bb += 4)
      tile[bb][lane] = x[(size_t)bb * N_NEUR + n0 + lane];
    __syncthreads();
    #pragma unroll
    for (int nn = w; nn < 64; nn += 4)
      xtb[(size_t)(n0 + nn) * 64 + lane] = f2bf(tile[lane][nn]);
  } else {
    int* lh = (int*)smem;                    // 4096 counters
    #pragma unroll
    for (int q = 0; q < NBUK / 256; ++q) lh[q * 256 + t] = 0;
    __syncthreads();
    const int e0 = (blockIdx.x - 1024) * EPB;
    #pragma unroll
    for (int k = 0; k < EPB / 256; ++k)
      atomicAdd(&lh[rows[e0 + k * 256 + t] >> BSH], 1);
    __syncthreads();
    #pragma unroll
    for (int q = 0; q < NBUK / 256; ++q) {
      const int v = lh[q * 256 + t];
      if (v) atomicAdd(&bcnt[q * 256 + t], v);
    }
  }
}

// ---------------- K2: exclusive scan over 4096 bucket counts (1 block) ----------------
__device__ inline int wave_incl_scan(int v, int lane) {
  #pragma unroll
  for (int off = 1; off < 64; off <<= 1) {
    int tv = __shfl_up(v, off, 64);
    if (lane >= off) v += tv;
  }
  return v;
}

__global__ __launch_bounds__(256) void k_bscan(const int* __restrict__ bcnt,
                                               int* __restrict__ boffs,
                                               int* __restrict__ gcur) {
  const int t = threadIdx.x, lane = t & 63, w = t >> 6;
  int c[16], s = 0;
  #pragma unroll
  for (int k = 0; k < 16; ++k) { c[k] = bcnt[t * 16 + k]; s += c[k]; }
  int incl = wave_incl_scan(s, lane);
  __shared__ int wsum[4];
  if (lane == 63) wsum[w] = incl;
  __syncthreads();
  int base = 0;
  for (int i = 0; i < w; ++i) base += wsum[i];
  int run = base + incl - s;
  #pragma unroll
  for (int k = 0; k < 16; ++k) {
    boffs[t * 16 + k] = run;
    gcur[t * 16 + k]  = run;
    run += c[k];
  }
}

// ---------------- K3: bucket-bin edges with coalesced chunk writes ----------------
// lc doubles as sbase after the reservation phase
__global__ __launch_bounds__(256) void k_bin(const int* __restrict__ rows,
                                             const float* __restrict__ vals,
                                             int* __restrict__ gcur,
                                             uint64_t* __restrict__ csr) {
  __shared__ int lc[NBUK];        // 16 KB  (count, then sbase)
  __shared__ int lofs[NBUK];      // 16 KB  (scan, then cursor)
  __shared__ int wsum[4];
  __shared__ uint64_t ebuf[EPB];  // 32 KB
  const int t = threadIdx.x, lane = t & 63, w = t >> 6;
  #pragma unroll
  for (int q = 0; q < NBUK / 256; ++q) lc[q * 256 + t] = 0;
  __syncthreads();
  const int e0 = blockIdx.x * EPB;
  int rcache[EPB / 256];
  #pragma unroll
  for (int k = 0; k < EPB / 256; ++k) {
    const int r = rows[e0 + k * 256 + t];
    rcache[k] = r;
    atomicAdd(&lc[r >> BSH], 1);
  }
  __syncthreads();
  {  // exclusive scan lc[4096] -> lofs (thread-chunked 16)
    int c[16], s = 0;
    #pragma unroll
    for (int k = 0; k < 16; ++k) { c[k] = lc[t * 16 + k]; s += c[k]; }
    int incl = wave_incl_scan(s, lane);
    if (lane == 63) wsum[w] = incl;
    __syncthreads();
    int base = 0;
    for (int i = 0; i < w; ++i) base += wsum[i];
    int run = base + incl - s;
    #pragma unroll
    for (int k = 0; k < 16; ++k) { lofs[t * 16 + k] = run; run += c[k]; }
  }
  __syncthreads();
  // reserve contiguous global chunk per non-empty bucket; lc[bb] := sbase
  #pragma unroll
  for (int q = 0; q < NBUK / 256; ++q) {
    const int bb = q * 256 + t;
    const int c = lc[bb];
    if (c) lc[bb] = atomicAdd(&gcur[bb], c) - lofs[bb];
  }
  __syncthreads();
  // local bucket-sort into ebuf (lofs doubles as cursor)
  #pragma unroll
  for (int k = 0; k < EPB / 256; ++k) {
    const int e = e0 + k * 256 + t;
    const int r = rcache[k];
    const uint32_t c = (uint32_t)e / 33u;      // cols[e] == e / 33 structurally
    const uint64_t pk = ((uint64_t)__float_as_uint(vals[e]) << 32) |
                        ((uint32_t)r << 16) | c;
    const int pos = atomicAdd(&lofs[r >> BSH], 1);
    ebuf[pos] = pk;
  }
  __syncthreads();
  // coalesced write-out: same-bucket runs -> consecutive global targets
  #pragma unroll
  for (int k = 0; k < EPB / 256; ++k) {
    const int idx = k * 256 + t;
    const uint64_t pk = ebuf[idx];
    const int bb = (int)((pk >> (16 + BSH)) & (NBUK - 1));
    csr[lc[bb] + idx] = pk;
  }
}

// ---------------- K4: per-bucket chunked sort (pad-to-8) + bf16 pair gather ------
// Half-wave h takes edge 2k+h of each pair; lane p in [0,32) loads one uint =
// bf16 batches (2p, 2p+1) of its half's edge. One 256B wave-instr covers 2 edges.
__global__ __launch_bounds__(256) void k_gather(const unsigned short* __restrict__ xtb,
                                                const int* __restrict__ boffs,
                                                const int* __restrict__ bcnt,
                                                const uint64_t* __restrict__ csr,
                                                float* __restrict__ out) {
  __shared__ uint64_t ebuf[EBUFSZ];    // 13.3 KB
  __shared__ float tile[BROWS][66];    // 4.2 KB (even stride for pair writes)
  __shared__ int lhist[BROWS], lofs[BROWS], lcur[BROWS], lpc[BROWS];
  const int t = threadIdx.x, lane = t & 63, w = t >> 6;
  const int h = lane >> 5, p = lane & 31;
  const int bid = blockIdx.x;
  const int g = (bid & 7) * (NBUK / 8) + (bid >> 3);   // XCD-chunked swizzle
  const int r0 = g * BROWS;
  const int beg = boffs[g];
  const int cnt = bcnt[g];
  const uint32_t* __restrict__ xtu = (const uint32_t*)xtb;  // [N][32] uints

  float accx[4] = {0.f, 0.f, 0.f, 0.f};   // wave w owns rows w*4 .. w*4+3
  float accy[4] = {0.f, 0.f, 0.f, 0.f};

  for (int c0 = 0; c0 < cnt; c0 += CHUNK) {
    const int len = (cnt - c0 < CHUNK) ? (cnt - c0) : CHUNK;
    if (t < BROWS) lhist[t] = 0;
    __syncthreads();
    // stage to regs + LDS row histogram (single coalesced csr read)
    uint64_t E[CHUNK / 256];
    #pragma unroll
    for (int u = 0; u < CHUNK / 256; ++u) {
      const int i = u * 256 + t;
      if (i < len) {
        const uint64_t e = csr[beg + c0 + i];
        E[u] = e;
        atomicAdd(&lhist[(int)((e >> 16) & (BROWS - 1))], 1);
      }
    }
    __syncthreads();
    if (t == 0) {
      int run = 0;
      #pragma unroll
      for (int r = 0; r < BROWS; ++r) {
        const int c = lhist[r];
        const int pc = (c + 7) & ~7;          // pad each row to multiple of 8
        lofs[r] = run; lcur[r] = run; lpc[r] = pc;
        run += pc;                            // run <= len + 112 <= EBUFSZ
      }
    }
    __syncthreads();
    // zero-fill pad slots (<=7 per row): t<128 covers 16 rows x 8 pad idx
    if (t < 128) {
      const int r = t >> 3, pi = t & 7;
      const int c = lhist[r];
      if (pi < lpc[r] - c) ebuf[lofs[r] + c + pi] = 0ULL;   // col 0, val 0: no-op
    }
    // scatter into row-sorted LDS order
    #pragma unroll
    for (int u = 0; u < CHUNK / 256; ++u) {
      const int i = u * 256 + t;
      if (i < len) {
        const int rlo = (int)((E[u] >> 16) & (BROWS - 1));
        const int pos = atomicAdd(&lcur[rlo], 1);
        ebuf[pos] = E[u];
      }
    }
    __syncthreads();
    // gather: wave w owns rows w*4..w*4+3; 8-pair main body + 4-pair tail
    #pragma unroll
    for (int q = 0; q < 4; ++q) {
      const int rlo = w * 4 + q;
      const int s = __builtin_amdgcn_readfirstlane(lofs[rlo]);
      const int npair = __builtin_amdgcn_readfirstlane(lpc[rlo]) >> 1; // mult of 4
      float ax = 0.f, ay = 0.f, bx = 0.f, by = 0.f;
      int ti = 0;
      for (; ti + 8 <= npair; ti += 8) {      // 16 edges in flight
        uint64_t e[8]; uint32_t xv[8];
        #pragma unroll
        for (int u = 0; u < 8; ++u) e[u] = ebuf[s + 2 * (ti + u) + h];
        #pragma unroll
        for (int u = 0; u < 8; ++u)
          xv[u] = xtu[(int)(e[u] & 0xFFFF) * 32 + p];     // 2 bf16 batches
        #pragma unroll
        for (int u = 0; u < 8; ++u) {
          const float v  = __uint_as_float((uint32_t)(e[u] >> 32));
          const float lo = __uint_as_float(xv[u] << 16);          // batch 2p
          const float hi = __uint_as_float(xv[u] & 0xFFFF0000u);  // batch 2p+1
          if (u & 1) { bx = fmaf(v, lo, bx); by = fmaf(v, hi, by); }
          else       { ax = fmaf(v, lo, ax); ay = fmaf(v, hi, ay); }
        }
      }
      if (ti < npair) {                        // exactly 4 pairs remain
        uint64_t e[4]; uint32_t xv[4];
        #pragma unroll
        for (int u = 0; u < 4; ++u) e[u] = ebuf[s + 2 * (ti + u) + h];
        #pragma unroll
        for (int u = 0; u < 4; ++u)
          xv[u] = xtu[(int)(e[u] & 0xFFFF) * 32 + p];
        #pragma unroll
        for (int u = 0; u < 4; ++u) {
          const float v  = __uint_as_float((uint32_t)(e[u] >> 32));
          const float lo = __uint_as_float(xv[u] << 16);
          const float hi = __uint_as_float(xv[u] & 0xFFFF0000u);
          if (u & 1) { bx = fmaf(v, lo, bx); by = fmaf(v, hi, by); }
          else       { ax = fmaf(v, lo, ax); ay = fmaf(v, hi, ay); }
        }
      }
      accx[q] += ax + bx;
      accy[q] += ay + by;
    }
    __syncthreads();   // ebuf/lhist reused next chunk
  }

  // combine halves (edge-parity split) and write tile
  #pragma unroll
  for (int q = 0; q < 4; ++q) {
    float sx = accx[q] + __shfl_xor(accx[q], 32, 64);
    float sy = accy[q] + __shfl_xor(accy[q], 32, 64);
    if (h == 0) {
      tile[w * 4 + q][2 * p]     = sx;
      tile[w * 4 + q][2 * p + 1] = sy;
    }
  }
  __syncthreads();
  // coalesced write-out: out[b][r0+rl]
  #pragma unroll
  for (int pp = 0; pp < (BROWS * 64) / 256; ++pp) {
    const int idx = pp * 256 + t;
    const int bb = idx >> 4;
    const int rl = idx & (BROWS - 1);
    out[(size_t)bb * N_NEUR + r0 + rl] = tile[rl][bb];
  }
}

extern "C" void kernel_launch(void* const* d_in, const int* in_sizes, int n_in,
                              void* d_out, int out_size, void* d_ws, size_t ws_size,
                              hipStream_t stream) {
  const float* x    = (const float*)d_in[0];
  const float* vals = (const float*)d_in[1];
  const int*   rows = (const int*)d_in[2];
  float* out = (float*)d_out;

  char* ws = (char*)d_ws;
  unsigned short* xtb = (unsigned short*)(ws + 0);
  int*      bcnt  = (int*)     (ws + 16777216);
  int*      boffs = (int*)     (ws + 16793600);
  int*      gcur  = (int*)     (ws + 16809984);
  uint64_t* csr   = (uint64_t*)(ws + 16826368);

  hipMemsetAsync(bcnt, 0, NBUK * sizeof(int), stream);
  k_front<<<1024 + NBLK_E, 256, 0, stream>>>(x, xtb, rows, bcnt);
  k_bscan<<<1, 256, 0, stream>>>(bcnt, boffs, gcur);
  k_bin<<<NBLK_E, 256, 0, stream>>>(rows, vals, gcur, csr);
  k_gather<<<NBUK, 256, 0, stream>>>(xtb, boffs, bcnt, csr, out);
}